// Round 2
// baseline (648.583 us; speedup 1.0000x reference)
//
#include <hip/hip_runtime.h>
#include <hip/hip_bf16.h>

// H=32 heads, M=512 queries, D=128, P=4096 KV rows, fp32 in/out.
// Output = multi-head attention only (reference's RMSNorm/QKV is dead code).
// Pass 1: flash attention over a KV partition (4-way split), unnormalized
//         O + (m,l) partials to workspace.  Pass 2: combine partitions.

#define NH   32
#define MQ   512
#define DD   128
#define PKV  4096
#define QBLK 64
#define KVB  64
#define VSTR 68            // Vt row stride (elems): 136B -> 8B-aligned quad reads
#define PSPLIT 4
#define NROW (NH * MQ)     // 16384 total q rows

typedef float  f32x4  __attribute__((ext_vector_type(4)));
typedef __bf16 bf16x4 __attribute__((ext_vector_type(4)));
typedef __bf16 bf16x8 __attribute__((ext_vector_type(8)));

__global__ __launch_bounds__(256, 4)
void attn_pass1(const float* __restrict__ qg,
                const float* __restrict__ kg,
                const float* __restrict__ vg,
                float* __restrict__ outg,        // direct-write path (partial==0)
                float* __restrict__ opart,       // [PSPLIT][NROW][DD] unnormalized
                float* __restrict__ mlpart,      // [PSPLIT][NROW][2]  (m, l)
                int ngshift, int nit, int partial)
{
    // K tile: row-major [64][128] bf16, XOR-swizzled (byte ^= (row&7)<<4)
    __shared__ __align__(16) __bf16 k_lds[KVB * DD];
    // V tile: transposed [128][68] bf16 with kv-rotation: element (kv,d) at
    //   vt[d*VSTR + ((kv + 4*((d>>2)&15)) & 63)]   (write-conflict killer)
    __shared__ __align__(16) __bf16 vt_lds[DD * VSTR];

    const int tid  = threadIdx.x;
    const int lane = tid & 63;
    const int w    = tid >> 6;      // wave 0..3, owns q-rows [16w,16w+16)
    const int q16  = lane & 15;
    const int hi   = lane >> 4;

    const int bx = blockIdx.x;
    const int g  = bx & ((1 << ngshift) - 1);  // group: same (h,p) -> same XCD
    const int qt = bx >> ngshift;              // q tile
    const int h  = g & 31;                     // head
    const int p  = g >> 5;                     // KV partition
    const int kvbase = p * nit * KVB;

    // ---- Q fragments: Q[rowq][32*ks + 8*hi + v], pre-scaled by scale*log2(e) ----
    const float SCL = 0.08838834764831845f * 1.4426950408889634f;
    const int rowq = qt * QBLK + w * 16 + q16;
    const float* qrow = qg + ((size_t)h * MQ + rowq) * DD;
    bf16x8 qf[4];
#pragma unroll
    for (int ks = 0; ks < 4; ++ks) {
        const float* ptr = qrow + ks * 32 + hi * 8;
        f32x4 a = *(const f32x4*)(ptr);
        f32x4 b = *(const f32x4*)(ptr + 4);
#pragma unroll
        for (int c = 0; c < 4; ++c) {
            qf[ks][c]     = (__bf16)(a[c] * SCL);
            qf[ks][c + 4] = (__bf16)(b[c] * SCL);
        }
    }

    // ---- staging assignment: thread covers (kv = 8j + srow, d = 4*(tid%32)) ----
    const int srow = tid >> 5;        // 0..7
    const int ii   = tid & 31;        // d-chunk index
    const int scol = ii * 4;          // 0..124
    const int vrot = 4 * (ii & 15);   // kv rotation for this thread's d-rows
    const float* kbase = kg + ((size_t)h * PKV + kvbase) * DD;
    const float* vbase = vg + ((size_t)h * PKV + kvbase) * DD;

    f32x4 kreg[8], vreg[8];
#pragma unroll
    for (int j = 0; j < 8; ++j) {
        size_t off = (size_t)(8 * j + srow) * DD + scol;
        kreg[j] = *(const f32x4*)(kbase + off);
        vreg[j] = *(const f32x4*)(vbase + off);
    }

    // ---- accumulator state ----
    f32x4 o[8];
#pragma unroll
    for (int dt = 0; dt < 8; ++dt) o[dt] = (f32x4){0.f, 0.f, 0.f, 0.f};
    float m_run = -1e30f;
    float l_run = 0.f;

    for (int it = 0; it < nit; ++it) {
        __syncthreads();   // previous tile's compute done -> LDS writable
#pragma unroll
        for (int j = 0; j < 8; ++j) {
            int kv = 8 * j + srow;
            bf16x4 pk;
#pragma unroll
            for (int c = 0; c < 4; ++c) pk[c] = (__bf16)kreg[j][c];
            int idx = kv * DD + (scol ^ ((kv & 7) << 3));   // K swizzle, b64-aligned
            *(bf16x4*)&k_lds[idx] = pk;
            int kvr = (kv + vrot) & 63;
#pragma unroll
            for (int c = 0; c < 4; ++c)
                vt_lds[(scol + c) * VSTR + kvr] = (__bf16)vreg[j][c];
        }
        __syncthreads();   // LDS ready

        // prefetch next tile (latency hides under MFMA/softmax below)
        if (it + 1 < nit) {
            const float* kb = kbase + (size_t)(it + 1) * KVB * DD;
            const float* vb = vbase + (size_t)(it + 1) * KVB * DD;
#pragma unroll
            for (int j = 0; j < 8; ++j) {
                size_t off = (size_t)(8 * j + srow) * DD + scol;
                kreg[j] = *(const f32x4*)(kb + off);
                vreg[j] = *(const f32x4*)(vb + off);
            }
        }

        // ---- S^T = K · Q^T : tile t covers kv [16t,16t+16); lane reg r = kv 16t+4hi+r, q=q16
        f32x4 st[4];
#pragma unroll
        for (int t = 0; t < 4; ++t) st[t] = (f32x4){0.f, 0.f, 0.f, 0.f};
        __builtin_amdgcn_s_setprio(1);
#pragma unroll
        for (int ks = 0; ks < 4; ++ks) {
#pragma unroll
            for (int t = 0; t < 4; ++t) {
                int kvrow = t * 16 + q16;
                int d0 = ks * 32 + hi * 8;
                bf16x8 kf = *(const bf16x8*)&k_lds[kvrow * DD + (d0 ^ ((kvrow & 7) << 3))];
                st[t] = __builtin_amdgcn_mfma_f32_16x16x32_bf16(kf, qf[ks], st[t], 0, 0, 0);
            }
        }
        __builtin_amdgcn_s_setprio(0);

        // ---- online softmax (scores already in log2 units) ----
        float mt = st[0][0];
#pragma unroll
        for (int t = 0; t < 4; ++t)
#pragma unroll
            for (int r = 0; r < 4; ++r) mt = fmaxf(mt, st[t][r]);
        mt = fmaxf(mt, __shfl_xor(mt, 16));
        mt = fmaxf(mt, __shfl_xor(mt, 32));
        float m_new = fmaxf(m_run, mt);
        float alpha = __builtin_amdgcn_exp2f(m_run - m_new);

        float lsum = 0.f;
        bf16x8 pa[2];   // PV A-frags: pa[c][v] = P[q16][32c + 16(v>>2) + 4hi + (v&3)]
#pragma unroll
        for (int t = 0; t < 4; ++t) {
#pragma unroll
            for (int r = 0; r < 4; ++r) {
                float pv = __builtin_amdgcn_exp2f(st[t][r] - m_new);
                lsum += pv;
                pa[t >> 1][(t & 1) * 4 + r] = (__bf16)pv;
            }
        }
        lsum += __shfl_xor(lsum, 16);
        lsum += __shfl_xor(lsum, 32);
        l_run = l_run * alpha + lsum;
        m_run = m_new;

        // rescale O (O rows are q = 4*hi + r; alpha lives at lane q)
        f32x4 av;
#pragma unroll
        for (int r = 0; r < 4; ++r) av[r] = __shfl(alpha, hi * 4 + r);
#pragma unroll
        for (int dt = 0; dt < 8; ++dt)
#pragma unroll
            for (int r = 0; r < 4; ++r) o[dt][r] *= av[r];

        // ---- O += P · V : B slot v = V[32c + 16(v>>2) + 4hi + (v&3)][16dt + q16] ----
        __builtin_amdgcn_s_setprio(1);
#pragma unroll
        for (int c = 0; c < 2; ++c) {
#pragma unroll
            for (int dt = 0; dt < 8; ++dt) {
                int drow = dt * 16 + q16;
                int rot = (16 * dt + 4 * (q16 >> 2)) & 63;   // = 4*((drow>>2)&15)
                int kb0 = (c * 32 + hi * 4 + rot) & 63;
                int kb1 = (c * 32 + hi * 4 + 16 + rot) & 63;
                bf16x4 v0 = *(const bf16x4*)&vt_lds[drow * VSTR + kb0];
                bf16x4 v1 = *(const bf16x4*)&vt_lds[drow * VSTR + kb1];
                bf16x8 vf;
#pragma unroll
                for (int e = 0; e < 4; ++e) { vf[e] = v0[e]; vf[e + 4] = v1[e]; }
                o[dt] = __builtin_amdgcn_mfma_f32_16x16x32_bf16(pa[c], vf, o[dt], 0, 0, 0);
            }
        }
        __builtin_amdgcn_s_setprio(0);
    }

    // ---- epilogue ----
    const int row0 = qt * QBLK + w * 16;
    if (partial) {
        const int rbase = h * MQ + row0;   // global row id (head-major)
        float* ob = opart + ((size_t)p * NROW + rbase) * DD;
#pragma unroll
        for (int dt = 0; dt < 8; ++dt)
#pragma unroll
            for (int r = 0; r < 4; ++r)
                ob[(size_t)(hi * 4 + r) * DD + dt * 16 + q16] = o[dt][r];
        if (lane < 16) {   // lane == q16
            size_t mi = ((size_t)p * NROW + rbase + lane) * 2;
            mlpart[mi]     = m_run;
            mlpart[mi + 1] = l_run;
        }
    } else {
        f32x4 linv;
#pragma unroll
        for (int r = 0; r < 4; ++r) linv[r] = 1.0f / __shfl(l_run, hi * 4 + r);
#pragma unroll
        for (int dt = 0; dt < 8; ++dt) {
#pragma unroll
            for (int r = 0; r < 4; ++r) {
                int row = row0 + hi * 4 + r;
                int col = h * DD + dt * 16 + q16;
                outg[(size_t)row * (NH * DD) + col] = o[dt][r] * linv[r];
            }
        }
    }
}

__global__ __launch_bounds__(256)
void attn_combine(const float* __restrict__ opart,
                  const float* __restrict__ mlpart,
                  float* __restrict__ outg)
{
    int idx = blockIdx.x * 256 + threadIdx.x;   // < NROW*32
    int r = idx >> 5;
    int c = idx & 31;

    float m[PSPLIT], l[PSPLIT];
#pragma unroll
    for (int p2 = 0; p2 < PSPLIT; ++p2) {
        size_t mi = ((size_t)p2 * NROW + r) * 2;
        m[p2] = mlpart[mi];
        l[p2] = mlpart[mi + 1];
    }
    float mstar = m[0];
#pragma unroll
    for (int p2 = 1; p2 < PSPLIT; ++p2) mstar = fmaxf(mstar, m[p2]);

    float denom = 0.f;
    f32x4 acc = (f32x4){0.f, 0.f, 0.f, 0.f};
#pragma unroll
    for (int p2 = 0; p2 < PSPLIT; ++p2) {
        float wgt = __builtin_amdgcn_exp2f(m[p2] - mstar);
        denom += wgt * l[p2];
        f32x4 ov = *(const f32x4*)&opart[(((size_t)p2 * NROW + r) << 7) + c * 4];
#pragma unroll
        for (int e = 0; e < 4; ++e) acc[e] += wgt * ov[e];
    }
    float dinv = 1.0f / denom;
    int mrow = r & 511;
    int hh   = r >> 9;
    f32x4 res;
#pragma unroll
    for (int e = 0; e < 4; ++e) res[e] = acc[e] * dinv;
    *(f32x4*)&outg[(size_t)mrow * (NH * DD) + hh * DD + c * 4] = res;
}

extern "C" void kernel_launch(void* const* d_in, const int* in_sizes, int n_in,
                              void* d_out, int out_size, void* d_ws, size_t ws_size,
                              hipStream_t stream) {
    (void)in_sizes; (void)n_in; (void)out_size;
    // inputs: 0=X (unused), 1=weight (unused), 2=W (unused), 3=q, 4=cache_K, 5=cache_V
    const float* q  = (const float*)d_in[3];
    const float* ck = (const float*)d_in[4];
    const float* cv = (const float*)d_in[5];
    float* out = (float*)d_out;

    const size_t needO  = (size_t)PSPLIT * NROW * DD * sizeof(float);   // 32 MiB
    const size_t needML = (size_t)PSPLIT * NROW * 2 * sizeof(float);    // 512 KiB

    if (ws_size >= needO + needML) {
        float* opart = (float*)d_ws;
        float* ml    = (float*)((char*)d_ws + needO);
        // grid: bx = g + 128*qt, g = p*32 + h  (same (h,p) group -> same XCD)
        attn_pass1<<<dim3(NH * PSPLIT * (MQ / QBLK)), dim3(256), 0, stream>>>(
            q, ck, cv, nullptr, opart, ml, 7, PKV / PSPLIT / KVB, 1);
        attn_combine<<<dim3(NROW * 32 / 256), dim3(256), 0, stream>>>(opart, ml, out);
    } else {
        attn_pass1<<<dim3(NH * (MQ / QBLK)), dim3(256), 0, stream>>>(
            q, ck, cv, out, nullptr, nullptr, 5, PKV / KVB, 0);
    }
}

// Round 3
// 406.805 us; speedup vs baseline: 1.5943x; 1.5943x over previous
//
#include <hip/hip_runtime.h>
#include <hip/hip_bf16.h>

// H=32 heads, M=512 queries, D=128, P=4096 KV rows, fp32 in/out.
// Output = multi-head attention only (reference's RMSNorm/QKV is dead code).
// Pass 1: flash attention over a KV partition (4-way split), unnormalized
//         O + (m,l) partials to workspace.  Pass 2: combine partitions.
//
// R2 lesson: __launch_bounds__(256,4) capped VGPRs at 64 -> 630 MB scratch
// spill traffic. Use (256,1); occupancy comes naturally (VGPR<=128, LDS 33KB
// -> 4 blocks/CU = 16 waves/CU).

#define NH   32
#define MQ   512
#define DD   128
#define PKV  4096
#define QBLK 64
#define KVB  64
#define VSTR 68            // Vt row stride (elems): 136B -> 8B-aligned quad reads
#define PSPLIT 4
#define NROW (NH * MQ)     // 16384 total q rows

typedef float  f32x4  __attribute__((ext_vector_type(4)));
typedef __bf16 bf16x4 __attribute__((ext_vector_type(4)));
typedef __bf16 bf16x8 __attribute__((ext_vector_type(8)));

__device__ __forceinline__ bf16x4 cvt_bf16x4(f32x4 a) {
    bf16x4 r;
#pragma unroll
    for (int c = 0; c < 4; ++c) r[c] = (__bf16)a[c];
    return r;
}

__global__ __launch_bounds__(256, 1)
void attn_pass1(const float* __restrict__ qg,
                const float* __restrict__ kg,
                const float* __restrict__ vg,
                float* __restrict__ outg,        // direct-write path (partial==0)
                float* __restrict__ opart,       // [PSPLIT][NROW][DD] unnormalized
                float* __restrict__ mlpart,      // [PSPLIT][NROW][2]  (m, l)
                int ngshift, int nit, int partial)
{
    // K tile: row-major [64][128] bf16, XOR-swizzled (byte ^= (row&7)<<4)
    __shared__ __align__(16) __bf16 k_lds[KVB * DD];
    // V tile: transposed [128][68] bf16 with kv-rotation: element (kv,d) at
    //   vt[d*VSTR + ((kv + 4*((d>>2)&15)) & 63)]   (write-conflict killer)
    __shared__ __align__(16) __bf16 vt_lds[DD * VSTR];

    const int tid  = threadIdx.x;
    const int lane = tid & 63;
    const int w    = tid >> 6;      // wave 0..3, owns q-rows [16w,16w+16)
    const int q16  = lane & 15;
    const int hi   = lane >> 4;

    const int bx = blockIdx.x;
    const int g  = bx & ((1 << ngshift) - 1);  // group: same (h,p) -> same XCD
    const int qt = bx >> ngshift;              // q tile
    const int h  = g & 31;                     // head
    const int p  = g >> 5;                     // KV partition
    const int kvbase = p * nit * KVB;

    // ---- Q fragments: Q[rowq][32*ks + 8*hi + v], pre-scaled by scale*log2(e) ----
    const float SCL = 0.08838834764831845f * 1.4426950408889634f;
    const int rowq = qt * QBLK + w * 16 + q16;
    const float* qrow = qg + ((size_t)h * MQ + rowq) * DD;
    bf16x8 qf[4];
#pragma unroll
    for (int ks = 0; ks < 4; ++ks) {
        const float* ptr = qrow + ks * 32 + hi * 8;
        f32x4 a = *(const f32x4*)(ptr);
        f32x4 b = *(const f32x4*)(ptr + 4);
#pragma unroll
        for (int c = 0; c < 4; ++c) {
            qf[ks][c]     = (__bf16)(a[c] * SCL);
            qf[ks][c + 4] = (__bf16)(b[c] * SCL);
        }
    }

    // ---- staging assignment: thread covers (kv = 8j + srow, d = 4*(tid%32)) ----
    const int srow = tid >> 5;        // 0..7
    const int ii   = tid & 31;        // d-chunk index
    const int scol = ii * 4;          // 0..124
    const int vrot = 4 * (ii & 15);   // kv rotation for this thread's d-rows
    const float* kbase = kg + ((size_t)h * PKV + kvbase) * DD;
    const float* vbase = vg + ((size_t)h * PKV + kvbase) * DD;

    // prefetch registers in bf16 (32 VGPRs total, halves R1's footprint)
    bf16x4 kreg[8], vreg[8];
#pragma unroll
    for (int j = 0; j < 8; ++j) {
        size_t off = (size_t)(8 * j + srow) * DD + scol;
        kreg[j] = cvt_bf16x4(*(const f32x4*)(kbase + off));
        vreg[j] = cvt_bf16x4(*(const f32x4*)(vbase + off));
    }

    // ---- accumulator state ----
    f32x4 o[8];
#pragma unroll
    for (int dt = 0; dt < 8; ++dt) o[dt] = (f32x4){0.f, 0.f, 0.f, 0.f};
    float m_run = -1e30f;
    float l_run = 0.f;

    for (int it = 0; it < nit; ++it) {
        __syncthreads();   // previous tile's compute done -> LDS writable
#pragma unroll
        for (int j = 0; j < 8; ++j) {
            int kv = 8 * j + srow;
            int idx = kv * DD + (scol ^ ((kv & 7) << 3));   // K swizzle, b64-aligned
            *(bf16x4*)&k_lds[idx] = kreg[j];
            int kvr = (kv + vrot) & 63;
#pragma unroll
            for (int c = 0; c < 4; ++c)
                vt_lds[(scol + c) * VSTR + kvr] = vreg[j][c];
        }
        __syncthreads();   // LDS ready

        // prefetch next tile (latency hides under MFMA/softmax below)
        if (it + 1 < nit) {
            const float* kb = kbase + (size_t)(it + 1) * KVB * DD;
            const float* vb = vbase + (size_t)(it + 1) * KVB * DD;
#pragma unroll
            for (int j = 0; j < 8; ++j) {
                size_t off = (size_t)(8 * j + srow) * DD + scol;
                kreg[j] = cvt_bf16x4(*(const f32x4*)(kb + off));
                vreg[j] = cvt_bf16x4(*(const f32x4*)(vb + off));
            }
        }

        // ---- S^T = K · Q^T : tile t covers kv [16t,16t+16); lane reg r = kv 16t+4hi+r, q=q16
        f32x4 st[4];
#pragma unroll
        for (int t = 0; t < 4; ++t) st[t] = (f32x4){0.f, 0.f, 0.f, 0.f};
        __builtin_amdgcn_s_setprio(1);
#pragma unroll
        for (int ks = 0; ks < 4; ++ks) {
#pragma unroll
            for (int t = 0; t < 4; ++t) {
                int kvrow = t * 16 + q16;
                int d0 = ks * 32 + hi * 8;
                bf16x8 kf = *(const bf16x8*)&k_lds[kvrow * DD + (d0 ^ ((kvrow & 7) << 3))];
                st[t] = __builtin_amdgcn_mfma_f32_16x16x32_bf16(kf, qf[ks], st[t], 0, 0, 0);
            }
        }
        __builtin_amdgcn_s_setprio(0);

        // ---- online softmax (scores already in log2 units) ----
        float mt = st[0][0];
#pragma unroll
        for (int t = 0; t < 4; ++t)
#pragma unroll
            for (int r = 0; r < 4; ++r) mt = fmaxf(mt, st[t][r]);
        mt = fmaxf(mt, __shfl_xor(mt, 16));
        mt = fmaxf(mt, __shfl_xor(mt, 32));
        float m_new = fmaxf(m_run, mt);
        float alpha = __builtin_amdgcn_exp2f(m_run - m_new);

        float lsum = 0.f;
        bf16x8 pa[2];   // PV A-frags: pa[c][v] = P[q16][32c + 16(v>>2) + 4hi + (v&3)]
#pragma unroll
        for (int t = 0; t < 4; ++t) {
#pragma unroll
            for (int r = 0; r < 4; ++r) {
                float pv = __builtin_amdgcn_exp2f(st[t][r] - m_new);
                lsum += pv;
                pa[t >> 1][(t & 1) * 4 + r] = (__bf16)pv;
            }
        }
        lsum += __shfl_xor(lsum, 16);
        lsum += __shfl_xor(lsum, 32);
        l_run = l_run * alpha + lsum;
        m_run = m_new;

        // rescale O (O rows are q = 4*hi + r; alpha lives at lane q)
        f32x4 av;
#pragma unroll
        for (int r = 0; r < 4; ++r) av[r] = __shfl(alpha, hi * 4 + r);
#pragma unroll
        for (int dt = 0; dt < 8; ++dt)
#pragma unroll
            for (int r = 0; r < 4; ++r) o[dt][r] *= av[r];

        // ---- O += P · V : B slot v = V[32c + 16(v>>2) + 4hi + (v&3)][16dt + q16] ----
        __builtin_amdgcn_s_setprio(1);
#pragma unroll
        for (int c = 0; c < 2; ++c) {
#pragma unroll
            for (int dt = 0; dt < 8; ++dt) {
                int drow = dt * 16 + q16;
                int rot = (16 * dt + 4 * (q16 >> 2)) & 63;   // = 4*((drow>>2)&15)
                int kb0 = (c * 32 + hi * 4 + rot) & 63;
                int kb1 = (c * 32 + hi * 4 + 16 + rot) & 63;
                bf16x4 v0 = *(const bf16x4*)&vt_lds[drow * VSTR + kb0];
                bf16x4 v1 = *(const bf16x4*)&vt_lds[drow * VSTR + kb1];
                bf16x8 vf;
#pragma unroll
                for (int e = 0; e < 4; ++e) { vf[e] = v0[e]; vf[e + 4] = v1[e]; }
                o[dt] = __builtin_amdgcn_mfma_f32_16x16x32_bf16(pa[c], vf, o[dt], 0, 0, 0);
            }
        }
        __builtin_amdgcn_s_setprio(0);
    }

    // ---- epilogue ----
    const int row0 = qt * QBLK + w * 16;
    if (partial) {
        const int rbase = h * MQ + row0;   // global row id (head-major)
        float* ob = opart + ((size_t)p * NROW + rbase) * DD;
#pragma unroll
        for (int dt = 0; dt < 8; ++dt)
#pragma unroll
            for (int r = 0; r < 4; ++r)
                ob[(size_t)(hi * 4 + r) * DD + dt * 16 + q16] = o[dt][r];
        if (lane < 16) {   // lane == q16
            size_t mi = ((size_t)p * NROW + rbase + lane) * 2;
            mlpart[mi]     = m_run;
            mlpart[mi + 1] = l_run;
        }
    } else {
        f32x4 linv;
#pragma unroll
        for (int r = 0; r < 4; ++r) linv[r] = 1.0f / __shfl(l_run, hi * 4 + r);
#pragma unroll
        for (int dt = 0; dt < 8; ++dt) {
#pragma unroll
            for (int r = 0; r < 4; ++r) {
                int row = row0 + hi * 4 + r;
                int col = h * DD + dt * 16 + q16;
                outg[(size_t)row * (NH * DD) + col] = o[dt][r] * linv[r];
            }
        }
    }
}

__global__ __launch_bounds__(256)
void attn_combine(const float* __restrict__ opart,
                  const float* __restrict__ mlpart,
                  float* __restrict__ outg)
{
    int idx = blockIdx.x * 256 + threadIdx.x;   // < NROW*32
    int r = idx >> 5;
    int c = idx & 31;

    float m[PSPLIT], l[PSPLIT];
#pragma unroll
    for (int p2 = 0; p2 < PSPLIT; ++p2) {
        size_t mi = ((size_t)p2 * NROW + r) * 2;
        m[p2] = mlpart[mi];
        l[p2] = mlpart[mi + 1];
    }
    float mstar = m[0];
#pragma unroll
    for (int p2 = 1; p2 < PSPLIT; ++p2) mstar = fmaxf(mstar, m[p2]);

    float denom = 0.f;
    f32x4 acc = (f32x4){0.f, 0.f, 0.f, 0.f};
#pragma unroll
    for (int p2 = 0; p2 < PSPLIT; ++p2) {
        float wgt = __builtin_amdgcn_exp2f(m[p2] - mstar);
        denom += wgt * l[p2];
        f32x4 ov = *(const f32x4*)&opart[(((size_t)p2 * NROW + r) << 7) + c * 4];
#pragma unroll
        for (int e = 0; e < 4; ++e) acc[e] += wgt * ov[e];
    }
    float dinv = 1.0f / denom;
    int mrow = r & 511;
    int hh   = r >> 9;
    f32x4 res;
#pragma unroll
    for (int e = 0; e < 4; ++e) res[e] = acc[e] * dinv;
    *(f32x4*)&outg[(size_t)mrow * (NH * DD) + hh * DD + c * 4] = res;
}

extern "C" void kernel_launch(void* const* d_in, const int* in_sizes, int n_in,
                              void* d_out, int out_size, void* d_ws, size_t ws_size,
                              hipStream_t stream) {
    (void)in_sizes; (void)n_in; (void)out_size;
    // inputs: 0=X (unused), 1=weight (unused), 2=W (unused), 3=q, 4=cache_K, 5=cache_V
    const float* q  = (const float*)d_in[3];
    const float* ck = (const float*)d_in[4];
    const float* cv = (const float*)d_in[5];
    float* out = (float*)d_out;

    const size_t needO  = (size_t)PSPLIT * NROW * DD * sizeof(float);   // 32 MiB
    const size_t needML = (size_t)PSPLIT * NROW * 2 * sizeof(float);    // 512 KiB

    if (ws_size >= needO + needML) {
        float* opart = (float*)d_ws;
        float* ml    = (float*)((char*)d_ws + needO);
        // grid: bx = g + 128*qt, g = p*32 + h  (same (h,p) group -> same XCD)
        attn_pass1<<<dim3(NH * PSPLIT * (MQ / QBLK)), dim3(256), 0, stream>>>(
            q, ck, cv, nullptr, opart, ml, 7, PKV / PSPLIT / KVB, 1);
        attn_combine<<<dim3(NROW * 32 / 256), dim3(256), 0, stream>>>(opart, ml, out);
    } else {
        attn_pass1<<<dim3(NH * (MQ / QBLK)), dim3(256), 0, stream>>>(
            q, ck, cv, out, nullptr, nullptr, 5, PKV / KVB, 0);
    }
}